// Round 6
// baseline (103.571 us; speedup 1.0000x reference)
//
#include <hip/hip_runtime.h>
#include <math.h>

#define CIN   3
#define COUT  16
#define DHW   64
#define WPAD  28                      // 27 weights padded to 28 -> every group 16B-aligned

typedef float v2f __attribute__((ext_vector_type(2)));

static __device__ __forceinline__ v2f splat2(float s) { v2f r; r.x = s; r.y = s; return r; }

// One thread per FOUR output voxels (n,d,h,w0..w0+3), as two packed fp32 pairs
// (v_pk_fma_f32). Weights staged in LDS, read as ds_read_b128.
//
// R5 post-mortem: 336 ds_read_b128/wave x 8192 waves = 54us of LDS-pipe time
// at 12cyc/instr -> LDS-issue-bound. Doubling voxels/thread halves LDS reads
// per voxel (floor 54 -> 27us); pk-FMA issue (8.6us total) is on another pipe.
//
// ConvTranspose3d(k=3,s=2,p=1,op=1) + MaxPool3d(2,2) fused:
//   od = 2*id - 1 + kd  =>  kd==1 -> even pool pos, id=d ; kd==0 -> odd, id=d+1 ;
//   kd==2 -> odd, id=d.  Each of 27 taps hits exactly one of 8 pool positions.
__global__ __launch_bounds__(256, 2) void fused_convt_pool_softmax_swish_max(
    const float* __restrict__ x,      // [N,CIN,64,64,64]
    const float* __restrict__ w,      // [CIN,COUT,3,3,3]
    const float* __restrict__ bias,   // [COUT]
    const float* __restrict__ sub,    // [COUT]
    float* __restrict__ out)          // [N,64,64,64]
{
    __shared__ float wsm[CIN * COUT * WPAD];         // 48*28*4 = 5376 B

    const int tid = threadIdx.y * 16 + threadIdx.x;
    for (int i = tid; i < CIN * COUT * 27; i += 256) {   // coalesced staging
        const int g = i / 27, r = i - g * 27;
        wsm[g * WPAD + r] = w[i];
    }
    __syncthreads();

    const int tx = threadIdx.x;                      // w-quad index, 0..15
    const int h  = blockIdx.x * blockDim.y + threadIdx.y;
    const int d  = blockIdx.y;
    const int n  = blockIdx.z;
    const int w0 = tx * 4;                           // outputs w0..w0+3; inputs w0..w0+4

    // P[c][dd][hh][j] = { x[w0+j], x[w0+j+1] }, j = 0..3
    v2f P[CIN][2][2][4];
    const size_t nbase = (size_t)n * CIN * DHW * DHW * DHW;
    const bool w4ok = (w0 + 4 < DHW);
    const int  off4 = w4ok ? 4 : 0;                  // clamped offset, stays in-bounds
#pragma unroll
    for (int c = 0; c < CIN; ++c) {
#pragma unroll
        for (int dd = 0; dd < 2; ++dd) {
#pragma unroll
            for (int hh = 0; hh < 2; ++hh) {
                const int id = d + dd;
                const int ih = h + hh;
                float4 q = make_float4(0.f, 0.f, 0.f, 0.f);
                float x4 = 0.0f;
                if (id < DHW && ih < DHW) {
                    const float* row = x + nbase + (((size_t)c * DHW + id) * DHW + ih) * DHW + w0;
                    q = *(const float4*)row;                  // 16B-aligned (w0 = 4*tx)
                    const float t = row[off4];
                    x4 = w4ok ? t : 0.0f;
                }
                v2f p0; p0.x = q.x; p0.y = q.y;
                v2f p1; p1.x = q.y; p1.y = q.z;
                v2f p2; p2.x = q.z; p2.y = q.w;
                v2f p3; p3.x = q.w; p3.y = x4;
                P[c][dd][hh][0] = p0;
                P[c][dd][hh][1] = p1;
                P[c][dd][hh][2] = p2;
                P[c][dd][hh][3] = p3;
            }
        }
    }

    v2f pooled[2][COUT];                             // [w-pair p][co]
#pragma unroll
    for (int co = 0; co < COUT; ++co) {
        v2f acc[2][2][2][2];                         // [p][pd][ph][pw]
#pragma unroll
        for (int i = 0; i < 16; ++i) (&acc[0][0][0][0])[i] = splat2(0.0f);
#pragma unroll
        for (int c = 0; c < CIN; ++c) {
            // 28-float group, 16B-aligned -> 7x ds_read_b128 (wave-broadcast)
            const float4* wq = (const float4*)&wsm[(c * COUT + co) * WPAD];
            float4 qw[7];
#pragma unroll
            for (int t = 0; t < 7; ++t) qw[t] = wq[t];
            const float* wf = (const float*)&qw[0];  // wf[0..26], compile-time idx
#pragma unroll
            for (int kd = 0; kd < 3; ++kd) {
                const int pd = (kd == 1) ? 0 : 1;
                const int dd = (kd == 0) ? 1 : 0;
#pragma unroll
                for (int kh = 0; kh < 3; ++kh) {
                    const int ph = (kh == 1) ? 0 : 1;
                    const int hh = (kh == 0) ? 1 : 0;
#pragma unroll
                    for (int kw = 0; kw < 3; ++kw) {
                        const int pw = (kw == 1) ? 0 : 1;
                        const int ww = (kw == 0) ? 1 : 0;
                        const float wt = wf[kd * 9 + kh * 3 + kw];
#pragma unroll
                        for (int p = 0; p < 2; ++p)  // voxels (w0+2p, w0+2p+1)
                            acc[p][pd][ph][pw] = __builtin_elementwise_fma(
                                splat2(wt), P[c][dd][hh][2 * p + ww], acc[p][pd][ph][pw]);
                    }
                }
            }
        }
        const float bco = bias[co];
#pragma unroll
        for (int p = 0; p < 2; ++p) {
            const v2f* a = &acc[p][0][0][0];
            v2f m0 = __builtin_elementwise_max(__builtin_elementwise_max(a[0], a[1]), a[2]);
            v2f m1 = __builtin_elementwise_max(__builtin_elementwise_max(a[3], a[4]), a[5]);
            v2f m2 = __builtin_elementwise_max(__builtin_elementwise_max(a[6], a[7]), m0);
            pooled[p][co] = __builtin_elementwise_max(m1, m2) + splat2(bco);
        }
    }

    // channel softmax + subtract + swish + channel max, packed per w-pair.
    // swish monotone for z > -1.2785; z = softmax - sub >= -max|sub| ~ -0.3,
    // so max_co swish(z_co) = swish(max_co z_co).
    float4 resq;
    float* resf = (float*)&resq;
#pragma unroll
    for (int p = 0; p < 2; ++p) {
        v2f m = pooled[p][0];
#pragma unroll
        for (int co = 1; co < COUT; ++co) m = __builtin_elementwise_max(m, pooled[p][co]);
        v2f e[COUT];
        v2f s = splat2(0.0f);
#pragma unroll
        for (int co = 0; co < COUT; ++co) {
            v2f t = pooled[p][co] - m;
            v2f ev; ev.x = __expf(t.x); ev.y = __expf(t.y);
            e[co] = ev;
            s += ev;
        }
        v2f inv; inv.x = __builtin_amdgcn_rcpf(s.x); inv.y = __builtin_amdgcn_rcpf(s.y);
        v2f zmax = splat2(-3.402823466e+38f);
#pragma unroll
        for (int co = 0; co < COUT; ++co)
            zmax = __builtin_elementwise_max(
                zmax, __builtin_elementwise_fma(e[co], inv, splat2(-sub[co])));
        resf[2 * p + 0] = zmax.x * __builtin_amdgcn_rcpf(1.0f + __expf(-zmax.x));
        resf[2 * p + 1] = zmax.y * __builtin_amdgcn_rcpf(1.0f + __expf(-zmax.y));
    }

    float* op = out + (((size_t)n * DHW + d) * DHW + h) * DHW + w0;
    *(float4*)op = resq;                             // coalesced 16B store
}

extern "C" void kernel_launch(void* const* d_in, const int* in_sizes, int n_in,
                              void* d_out, int out_size, void* d_ws, size_t ws_size,
                              hipStream_t stream) {
    const float* x   = (const float*)d_in[0];
    const float* w   = (const float*)d_in[1];
    const float* b   = (const float*)d_in[2];
    const float* sub = (const float*)d_in[3];
    float* out = (float*)d_out;

    dim3 block(16, 16, 1);                // 16 w-quads x 16 h-rows = 256 threads
    dim3 grid(DHW / 16, DHW, 4);          // (h-groups, d, n)
    fused_convt_pool_softmax_swish_max<<<grid, block, 0, stream>>>(x, w, b, sub, out);
}